// Round 12
// baseline (100.631 us; speedup 1.0000x reference)
//
#include <hip/hip_runtime.h>
#include <stdint.h>

// PlaceCellNetwork — 50 fixed-point Jacobi iterations, per-row independent.
//
// R12 = R11 (MFMA formulation, PASSED, absmax 0.125) + 2x ILP:
//   8 tiles per wave (128 rows/wave, 512 rows/block) instead of 4.
// R11 post-mortem: kernel dropped below the harness's 44us poison-fills
// (bench-overhead arithmetic => ~37-40us). Remaining gap vs the ~7us issue
// model is per-chain serialization: each tile's mfma->cvt->pk_max->mfma is
// a ~30cyc dependency loop. 8 chains/wave x ~4 waves/SIMD ~= 30 concurrent
// chains fully covers MFMA result-read hazards; prologue (W/b gather)
// amortizes over 2x rows. Also: z1 = relu(c) computed directly (z0 = 0),
// saving one MFMA round (48 in-loop + 1 final = 50 transitions exactly).
//
// Formulation: z' = relu(G^T z + c) as v_mfma_f32_16x16x16f16:
//   M = output j (10/16), N = batch rows (16/tile), K = state k (10/16).
//   A[m][k]=G[k][m]: lane = m + 16*(k/4), elem = k%4
//   B[k][n]:         lane = n + 16*(k/4), elem = k%4
//   D[m][n]:         lane = n + 16*(m/4), elem = m%4   (== B's mapping)
// => D -> cvt_pkrtz -> v_pk_max -> next B, zero cross-lane movement.
// c is the C operand; padded rows/cols zeroed so padding stays exactly 0.
//   G[j][j]=(1-dt)*rd_j ; G[k][j]=-dt*rd_k*M_kj ; rd_j=1/(lbd2+M_jj)
//   c_j = dt*(Wx_j - b_j) - lbd1 ;  Y_j = rd_j * z_j.

typedef _Float16 h2 __attribute__((ext_vector_type(2)));
typedef _Float16 h4 __attribute__((ext_vector_type(4)));
typedef float    f4 __attribute__((ext_vector_type(4)));

constexpr int IN_DIM  = 5;
constexpr int OUT_DIM = 10;
constexpr int ITERS   = 50;
constexpr int NT      = 8;              // tiles per wave
constexpr float DT = 0.05f, LBD1 = 0.005f, LBD2 = 0.005f;

#if defined(__HIP_DEVICE_COMPILE__)
  #define MFMA16(a, b, c) __builtin_amdgcn_mfma_f32_16x16x16f16((a), (b), (c), 0, 0, 0)
#else
  #define MFMA16(a, b, c) (c)           // host pass: parse-only
#endif

__device__ __forceinline__ h2 cvt_pk(float a, float b) {
    return __builtin_bit_cast(h2, __builtin_amdgcn_cvt_pkrtz(a, b));
}

__global__ __launch_bounds__(256, 1) void pcn_kernel(
    const float* __restrict__ X,    // [n, 5]
    const float* __restrict__ W,    // [10, 5]
    const float* __restrict__ Mg,   // [10, 10]
    const float* __restrict__ b,    // [10]
    float* __restrict__ out,        // [n, 10]
    int n)
{
    // ---- build G (f32) + rd in LDS, once per block ----
    __shared__ float gtab[100];     // G[k][j]
    __shared__ float rdtab[OUT_DIM];
    int tid = threadIdx.x;
    if (tid < 100) {
        int k = tid / 10, j = tid % 10;
        float rdk = 1.0f / (LBD2 + Mg[k * 10 + k]);
        float rdj = 1.0f / (LBD2 + Mg[j * 10 + j]);
        gtab[tid] = (k == j) ? (1.0f - DT) * rdj : -DT * rdk * Mg[k * 10 + j];
        if (tid < OUT_DIM) rdtab[tid] = rdj;
    }
    __syncthreads();

    const int lane = tid & 63;
    const int w    = tid >> 6;      // wave in block (0..3)
    const int grp  = lane >> 4;     // element group (0..3)
    const int r16  = lane & 15;     // N-index within tile

    // ---- A fragment: A[m][k] = G[k][m]; lane m=r16, k=grp*4+e ----
    h4 afrag;
#pragma unroll
    for (int e = 0; e < 4; ++e) {
        int k = grp * 4 + e;
        float g = (k < OUT_DIM && r16 < OUT_DIM) ? gtab[k * 10 + r16] : 0.0f;
        afrag[e] = (_Float16)g;
    }

    // ---- per-lane j-set data (m = grp*4+e in C/D layout) ----
    float rdv[4], Wj[4][IN_DIM], bj[4];
#pragma unroll
    for (int e = 0; e < 4; ++e) {
        int j = grp * 4 + e;
        if (j < OUT_DIM) {
            rdv[e] = rdtab[j];
            bj[e]  = b[j];
#pragma unroll
            for (int d = 0; d < IN_DIM; ++d) Wj[e][d] = W[j * IN_DIM + d];
        } else {
            rdv[e] = 0.0f; bj[e] = 0.0f;
#pragma unroll
            for (int d = 0; d < IN_DIM; ++d) Wj[e][d] = 0.0f;
        }
    }

    // ---- per-tile c fragments (C operand), 8 tiles ----
    const long base = (long)blockIdx.x * (64 * NT) + (long)w * (16 * NT);
    f4 cf[NT];
#pragma unroll
    for (int t = 0; t < NT; ++t) {
        long r = base + t * 16 + r16;
        float x[IN_DIM];
        if (r < n) {
#pragma unroll
            for (int d = 0; d < IN_DIM; ++d) x[d] = X[r * IN_DIM + d];
        } else {
#pragma unroll
            for (int d = 0; d < IN_DIM; ++d) x[d] = 0.0f;
        }
#pragma unroll
        for (int e = 0; e < 4; ++e) {
            int j = grp * 4 + e;
            if (j < OUT_DIM) {
                float s = -bj[e];
#pragma unroll
                for (int d = 0; d < IN_DIM; ++d) s = fmaf(x[d], Wj[e][d], s);
                cf[t][e] = fmaf(DT, s, -LBD1);
            } else {
                cf[t][e] = 0.0f;    // padding stays exactly 0
            }
        }
    }

    h2 zero2; zero2.x = (_Float16)0.0f; zero2.y = (_Float16)0.0f;

    // ---- iteration 1 free: z1 = relu(c) (z0 = 0) ----
    h4 B[NT];
#pragma unroll
    for (int t = 0; t < NT; ++t) {
        h2 lo = __builtin_elementwise_max(cvt_pk(cf[t][0], cf[t][1]), zero2);
        h2 hi = __builtin_elementwise_max(cvt_pk(cf[t][2], cf[t][3]), zero2);
        B[t][0] = lo.x; B[t][1] = lo.y; B[t][2] = hi.x; B[t][3] = hi.y;
    }

    // ---- iterations 2..49: mfma chains, 8-way ILP ----
#pragma unroll 1
    for (int it = 0; it < ITERS - 2; ++it) {
#pragma unroll
        for (int t = 0; t < NT; ++t) {
            f4 acc = MFMA16(afrag, B[t], cf[t]);
            h2 lo = __builtin_elementwise_max(cvt_pk(acc[0], acc[1]), zero2);
            h2 hi = __builtin_elementwise_max(cvt_pk(acc[2], acc[3]), zero2);
            B[t][0] = lo.x; B[t][1] = lo.y; B[t][2] = hi.x; B[t][3] = hi.y;
        }
    }

    // ---- iteration 50 in f32 + scaled store: Y[r][j] = rd_j * z_j ----
#pragma unroll
    for (int t = 0; t < NT; ++t) {
        f4 acc = MFMA16(afrag, B[t], cf[t]);
        long r = base + t * 16 + r16;
        if (r < n) {
            float y0 = fmaxf(acc[0], 0.0f) * rdv[0];
            float y1 = fmaxf(acc[1], 0.0f) * rdv[1];
            float y2 = fmaxf(acc[2], 0.0f) * rdv[2];
            float y3 = fmaxf(acc[3], 0.0f) * rdv[3];
            float* o = out + r * OUT_DIM + grp * 4;
            if (grp < 2) {                    // j 0-3 / 4-7
                *(float2*)(o)     = make_float2(y0, y1);
                *(float2*)(o + 2) = make_float2(y2, y3);
            } else if (grp == 2) {            // j 8-9
                *(float2*)(o)     = make_float2(y0, y1);
            }                                  // grp==3: nothing
        }
    }
}

extern "C" void kernel_launch(void* const* d_in, const int* in_sizes, int n_in,
                              void* d_out, int out_size, void* d_ws, size_t ws_size,
                              hipStream_t stream) {
    const float* X = (const float*)d_in[0];
    const float* W = (const float*)d_in[1];
    const float* M = (const float*)d_in[2];
    const float* b = (const float*)d_in[3];
    float* out = (float*)d_out;

    int n = in_sizes[0] / IN_DIM;           // 500000 rows
    int rows_per_block = 64 * NT;           // 4 waves x 8 tiles x 16 rows = 512
    int grid = (n + rows_per_block - 1) / rows_per_block;
    pcn_kernel<<<grid, 256, 0, stream>>>(X, W, M, b, out, n);
}

// Round 13
// 91.666 us; speedup vs baseline: 1.0978x; 1.0978x over previous
//
#include <hip/hip_runtime.h>
#include <stdint.h>

// PlaceCellNetwork — 50 fixed-point Jacobi iterations, per-row independent.
//
// R13 = R11 MFMA formulation + occupancy pin.
//
// R12 post-mortem: NT=8 (2x ILP, same total work) was neutral-to-worse vs
// NT=4 — so the loop isn't latency-bound at *current* occupancy, OR occupancy
// itself is the problem. Both R11/R12 left the VGPR cap open (min-waves=1):
// if the allocator crossed 256 VGPRs, occupancy = 1 wave/SIMD and every
// MFMA->VALU RAW hazard (s_nop wait states) + prologue load latency is fully
// exposed — matching the ~4x gap vs the ~10us issue model. Fix:
//   - __launch_bounds__(256, 4): cap 128 VGPRs -> >=4 waves/SIMD. Loop live
//     set ~60 regs, no spill risk.
//   - NT=4 (R11's better config).
//   - Two-phase loop body (all MFMAs, then all repacks) so hazard-covering
//     interleave is explicit.
//
// Formulation (R11, PASSED absmax 0.125): z' = relu(G^T z + c) as
// v_mfma_f32_16x16x16f16; M=output j (10/16), N=rows (16/tile), K=state k.
//   A[m][k]=G[k][m]: lane = m + 16*(k/4), elem = k%4
//   B[k][n]:         lane = n + 16*(k/4), elem = k%4
//   D[m][n]:         lane = n + 16*(m/4), elem = m%4  (== B's mapping)
// => D -> cvt_pkrtz -> v_pk_max -> next B, zero cross-lane movement.
// c rides as C operand; padded rows/cols zeroed. Iter 1 free (z1=relu(c)),
// final iter in f32 for the store. Y_j = rd_j * z_j.

typedef _Float16 h2 __attribute__((ext_vector_type(2)));
typedef _Float16 h4 __attribute__((ext_vector_type(4)));
typedef float    f4 __attribute__((ext_vector_type(4)));

constexpr int IN_DIM  = 5;
constexpr int OUT_DIM = 10;
constexpr int ITERS   = 50;
constexpr int NT      = 4;              // tiles per wave
constexpr float DT = 0.05f, LBD1 = 0.005f, LBD2 = 0.005f;

#if defined(__HIP_DEVICE_COMPILE__)
  #define MFMA16(a, b, c) __builtin_amdgcn_mfma_f32_16x16x16f16((a), (b), (c), 0, 0, 0)
#else
  #define MFMA16(a, b, c) (c)           // host pass: parse-only
#endif

__device__ __forceinline__ h2 cvt_pk(float a, float b) {
    return __builtin_bit_cast(h2, __builtin_amdgcn_cvt_pkrtz(a, b));
}

__global__ __launch_bounds__(256, 4) void pcn_kernel(
    const float* __restrict__ X,    // [n, 5]
    const float* __restrict__ W,    // [10, 5]
    const float* __restrict__ Mg,   // [10, 10]
    const float* __restrict__ b,    // [10]
    float* __restrict__ out,        // [n, 10]
    int n)
{
    // ---- build G (f32) + rd in LDS, once per block ----
    __shared__ float gtab[100];     // G[k][j]
    __shared__ float rdtab[OUT_DIM];
    int tid = threadIdx.x;
    if (tid < 100) {
        int k = tid / 10, j = tid % 10;
        float rdk = 1.0f / (LBD2 + Mg[k * 10 + k]);
        float rdj = 1.0f / (LBD2 + Mg[j * 10 + j]);
        gtab[tid] = (k == j) ? (1.0f - DT) * rdj : -DT * rdk * Mg[k * 10 + j];
        if (tid < OUT_DIM) rdtab[tid] = rdj;
    }
    __syncthreads();

    const int lane = tid & 63;
    const int w    = tid >> 6;      // wave in block (0..3)
    const int grp  = lane >> 4;     // element group (0..3)
    const int r16  = lane & 15;     // N-index within tile

    // ---- A fragment: A[m][k] = G[k][m]; lane m=r16, k=grp*4+e ----
    h4 afrag;
#pragma unroll
    for (int e = 0; e < 4; ++e) {
        int k = grp * 4 + e;
        float g = (k < OUT_DIM && r16 < OUT_DIM) ? gtab[k * 10 + r16] : 0.0f;
        afrag[e] = (_Float16)g;
    }

    // ---- per-lane j-set constants (m = grp*4+e in C/D layout) ----
    float rdv[4];
#pragma unroll
    for (int e = 0; e < 4; ++e) {
        int j = grp * 4 + e;
        rdv[e] = (j < OUT_DIM) ? rdtab[j] : 0.0f;
    }

    // ---- per-tile c fragments (C operand) ----
    const long base = (long)blockIdx.x * (64 * NT) + (long)w * (16 * NT);
    f4 cf[NT];
#pragma unroll
    for (int t = 0; t < NT; ++t) {
        long r = base + t * 16 + r16;
        float x[IN_DIM];
        if (r < n) {
#pragma unroll
            for (int d = 0; d < IN_DIM; ++d) x[d] = X[r * IN_DIM + d];
        } else {
#pragma unroll
            for (int d = 0; d < IN_DIM; ++d) x[d] = 0.0f;
        }
#pragma unroll
        for (int e = 0; e < 4; ++e) {
            int j = grp * 4 + e;
            if (j < OUT_DIM) {
                float s = -b[j];
#pragma unroll
                for (int d = 0; d < IN_DIM; ++d) s = fmaf(x[d], W[j * IN_DIM + d], s);
                cf[t][e] = fmaf(DT, s, -LBD1);
            } else {
                cf[t][e] = 0.0f;    // padding stays exactly 0
            }
        }
    }

    h2 zero2; zero2.x = (_Float16)0.0f; zero2.y = (_Float16)0.0f;

    // ---- iteration 1 free: z1 = relu(c) (z0 = 0) ----
    h4 B[NT];
#pragma unroll
    for (int t = 0; t < NT; ++t) {
        h2 lo = __builtin_elementwise_max(cvt_pk(cf[t][0], cf[t][1]), zero2);
        h2 hi = __builtin_elementwise_max(cvt_pk(cf[t][2], cf[t][3]), zero2);
        B[t][0] = lo.x; B[t][1] = lo.y; B[t][2] = hi.x; B[t][3] = hi.y;
    }

    // ---- iterations 2..49: two-phase body (all MFMAs, then all repacks) ----
#pragma unroll 1
    for (int it = 0; it < ITERS - 2; ++it) {
        f4 acc[NT];
#pragma unroll
        for (int t = 0; t < NT; ++t)
            acc[t] = MFMA16(afrag, B[t], cf[t]);
#pragma unroll
        for (int t = 0; t < NT; ++t) {
            h2 lo = __builtin_elementwise_max(cvt_pk(acc[t][0], acc[t][1]), zero2);
            h2 hi = __builtin_elementwise_max(cvt_pk(acc[t][2], acc[t][3]), zero2);
            B[t][0] = lo.x; B[t][1] = lo.y; B[t][2] = hi.x; B[t][3] = hi.y;
        }
    }

    // ---- iteration 50 in f32 + scaled store: Y[r][j] = rd_j * z_j ----
#pragma unroll
    for (int t = 0; t < NT; ++t) {
        f4 acc = MFMA16(afrag, B[t], cf[t]);
        long r = base + t * 16 + r16;
        if (r < n) {
            float y0 = fmaxf(acc[0], 0.0f) * rdv[0];
            float y1 = fmaxf(acc[1], 0.0f) * rdv[1];
            float y2 = fmaxf(acc[2], 0.0f) * rdv[2];
            float y3 = fmaxf(acc[3], 0.0f) * rdv[3];
            float* o = out + r * OUT_DIM + grp * 4;
            if (grp < 2) {                    // j 0-3 / 4-7
                *(float2*)(o)     = make_float2(y0, y1);
                *(float2*)(o + 2) = make_float2(y2, y3);
            } else if (grp == 2) {            // j 8-9
                *(float2*)(o)     = make_float2(y0, y1);
            }                                  // grp==3: nothing
        }
    }
}

extern "C" void kernel_launch(void* const* d_in, const int* in_sizes, int n_in,
                              void* d_out, int out_size, void* d_ws, size_t ws_size,
                              hipStream_t stream) {
    const float* X = (const float*)d_in[0];
    const float* W = (const float*)d_in[1];
    const float* M = (const float*)d_in[2];
    const float* b = (const float*)d_in[3];
    float* out = (float*)d_out;

    int n = in_sizes[0] / IN_DIM;           // 500000 rows
    int rows_per_block = 64 * NT;           // 4 waves x 4 tiles x 16 rows = 256
    int grid = (n + rows_per_block - 1) / rows_per_block;
    pcn_kernel<<<grid, 256, 0, stream>>>(X, W, M, b, out, n);
}